// Round 12
// baseline (783.011 us; speedup 1.0000x reference)
//
#include <hip/hip_runtime.h>
#include <hip/hip_bf16.h>

// Problem dims
#define Bn 2
#define Tn 4
#define NCc 3
#define NKc 16
#define Hc 180
#define Wc 320
#define HWc (Hc * Wc)          // 57600
#define NPIX (Bn * HWc)        // 115200
#define CIN_LSTM 19            // NC + NK
#define GATES 64               // 4*NK
#define CIN_D 64               // T*NK
#define TAPS_L (CIN_LSTM * 9)  // 171
#define TAPS_D (CIN_D * 9)     // 576
#define TAPS_O (NKc * 9)       // 144

typedef __hip_bfloat16 bf16;

__device__ __forceinline__ float getv(const float* p, long i) { return p[i]; }
__device__ __forceinline__ float getv(const bf16* p, long i) {
    unsigned int u = ((unsigned int)((const unsigned short*)p)[i]) << 16;
    return __uint_as_float(u);
}
__device__ __forceinline__ void putv(float* p, long i, float v) { p[i] = v; }
__device__ __forceinline__ void putv(bf16* p, long i, float v) { p[i] = __float2bfloat16(v); }
__device__ __forceinline__ float sigm(float x) { return 1.0f / (1.0f + __expf(-x)); }
__device__ __forceinline__ float tanh_(float x) { return 1.0f - 2.0f / (__expf(2.0f * x) + 1.0f); }

__device__ __forceinline__ void load4(const float* row, int x0, float* d) {
    const float4 v = *(const float4*)(row + x0);
    d[0] = v.x; d[1] = v.y; d[2] = v.z; d[3] = v.w;
}
__device__ __forceinline__ void load4(const bf16* row, int x0, float* d) {
    ushort4 u = *(const ushort4*)((const unsigned short*)row + x0);
    d[0] = __uint_as_float(((unsigned int)u.x) << 16);
    d[1] = __uint_as_float(((unsigned int)u.y) << 16);
    d[2] = __uint_as_float(((unsigned int)u.z) << 16);
    d[3] = __uint_as_float(((unsigned int)u.w) << 16);
}

// ---------------------------------------------------------------------------
// Dtype probe (bf16 vs float32 inputs) -> flag in d_ws.
// ---------------------------------------------------------------------------
__global__ void __launch_bounds__(256) k_detect(const void* lstm_w_raw, int* flag)
{
    __shared__ int bad;
    if (threadIdx.x == 0) bad = 0;
    __syncthreads();
    const unsigned short* u = (const unsigned short*)lstm_w_raw;
    int local = 0;
    for (int i = threadIdx.x; i < GATES * TAPS_L; i += 256) {
        unsigned int f32 = ((unsigned int)u[i]) << 16;
        float v = __uint_as_float(f32);
        if (!(fabsf(v) <= 64.0f)) local = 1;
    }
    if (local) atomicOr(&bad, 1);
    __syncthreads();
    if (threadIdx.x == 0) flag[0] = bad ? 0 : 1;
}

// ---------------------------------------------------------------------------
// ConvLSTM step (proven structure; ROUND-12: unroll 2 on h-plane cin loop).
// ---------------------------------------------------------------------------
template <typename S>
__device__ __forceinline__ void conv_plane(
    const S* __restrict__ src, int cin, int y, int x0, int kc,
    const float* __restrict__ sw, float (&acc)[4][4])
{
#pragma unroll
    for (int ky = 0; ky < 3; ky++) {
        int yy = y + ky - 1;
        if (yy < 0 || yy >= Hc) continue;
        const S* row = src + (long)yy * Wc;
        float xs[6];
        xs[0] = (x0 > 0) ? getv(row, x0 - 1) : 0.0f;
        load4(row, x0, &xs[1]);
        xs[5] = (x0 + 4 < Wc) ? getv(row, x0 + 4) : 0.0f;
#pragma unroll
        for (int kx = 0; kx < 3; kx++) {
            int tap = (cin * 3 + ky) * 3 + kx;
            const float4 wq = *(const float4*)&sw[(tap * 16 + kc) * 4];
#pragma unroll
            for (int px = 0; px < 4; px++) {
                float v = xs[px + kx];
                acc[0][px] += wq.x * v;
                acc[1][px] += wq.y * v;
                acc[2][px] += wq.z * v;
                acc[3][px] += wq.w * v;
            }
        }
    }
}

template <typename T>
__device__ __forceinline__ void lstm2_body(
    const T* __restrict__ X, const T* __restrict__ lstm_w, const T* __restrict__ lstm_b,
    const T* __restrict__ Wci, const T* __restrict__ Wcf, const T* __restrict__ Wco,
    float* __restrict__ c_buf, float* __restrict__ xcat, int t,
    float* sw, float* sb)
{
    for (int i = threadIdx.x; i < GATES * TAPS_L; i += 256) {
        int co = i / TAPS_L, tap = i - co * TAPS_L;
        int kc = co & 15, g = co >> 4;
        sw[(tap * 16 + kc) * 4 + g] = getv(lstm_w, i);
    }
    if (threadIdx.x < GATES) sb[threadIdx.x] = getv(lstm_b, threadIdx.x);
    __syncthreads();

    int blk = blockIdx.x;
    int seg = blk % 5; int rem = blk / 5;
    int y = rem % Hc; int b = rem / Hc;
    int kc = threadIdx.x >> 4, pl = threadIdx.x & 15;
    int x0 = seg * 64 + pl * 4;

    float acc[4][4];
#pragma unroll
    for (int px = 0; px < 4; px++) {
        acc[0][px] = sb[kc];
        acc[1][px] = sb[16 + kc];
        acc[2][px] = sb[32 + kc];
        acc[3][px] = sb[48 + kc];
    }

    const T* xt = X + (long)(b * Tn + t) * NCc * HWc;
#pragma unroll
    for (int cin = 0; cin < NCc; cin++)
        conv_plane(xt + (long)cin * HWc, cin, y, x0, kc, sw, acc);
    if (t > 0) {
        const float* hp = xcat + ((long)b * CIN_D + (t - 1) * NKc) * HWc;
#pragma unroll 2
        for (int cin = 0; cin < NKc; cin++)
            conv_plane(hp + (long)cin * HWc, cin + NCc, y, x0, kc, sw, acc);
    }

    long pbase = (long)y * Wc + x0;
    float* cb = c_buf + (long)(b * NKc + kc) * HWc + pbase;
    float cprev[4];
    if (t > 0) {
        const float4 cv = *(const float4*)cb;
        cprev[0] = cv.x; cprev[1] = cv.y; cprev[2] = cv.z; cprev[3] = cv.w;
    } else {
        cprev[0] = cprev[1] = cprev[2] = cprev[3] = 0.0f;
    }
    float wci[4], wcf[4], wco[4];
    load4(Wci + (long)kc * HWc + pbase, 0, wci);
    load4(Wcf + (long)kc * HWc + pbase, 0, wcf);
    load4(Wco + (long)kc * HWc + pbase, 0, wco);

    float cn4[4], h4[4];
#pragma unroll
    for (int px = 0; px < 4; px++) {
        float ii = sigm(acc[0][px] + wci[px] * cprev[px]);
        float ff = sigm(acc[1][px] + wcf[px] * cprev[px]);
        float cn = ff * cprev[px] + ii * tanh_(acc[2][px]);
        float oo = sigm(acc[3][px] + wco[px] * cn);
        cn4[px] = cn; h4[px] = oo * tanh_(cn);
    }
    *(float4*)cb = make_float4(cn4[0], cn4[1], cn4[2], cn4[3]);
    *(float4*)(xcat + ((long)b * CIN_D + t * NKc + kc) * HWc + pbase) =
        make_float4(h4[0], h4[1], h4[2], h4[3]);
}

__global__ void __launch_bounds__(256) k_lstm2(
    const void* X, const void* lstm_w, const void* lstm_b,
    const void* Wci, const void* Wcf, const void* Wco,
    const int* __restrict__ flag,
    float* c_buf, float* xcat, int t)
{
    __shared__ float sw[TAPS_L * GATES];  // 43.8 KB
    __shared__ float sb[GATES];
    if (flag[0])
        lstm2_body<bf16>((const bf16*)X, (const bf16*)lstm_w, (const bf16*)lstm_b,
                         (const bf16*)Wci, (const bf16*)Wcf, (const bf16*)Wco,
                         c_buf, xcat, t, sw, sb);
    else
        lstm2_body<float>((const float*)X, (const float*)lstm_w, (const float*)lstm_b,
                          (const float*)Wci, (const float*)Wcf, (const float*)Wco,
                          c_buf, xcat, t, sw, sb);
}

// ---------------------------------------------------------------------------
// offmod v6 (R10 output-split; ROUND-12: cin loops unroll 2 for MLP).
// ---------------------------------------------------------------------------
template <typename T>
__device__ __forceinline__ void offmod6_body(
    const float* __restrict__ xcat,
    const T* __restrict__ off_w, const T* __restrict__ off_b,
    const T* __restrict__ mod_w, const T* __restrict__ mod_b,
    float* __restrict__ offbuf, float* __restrict__ maskbuf,
    float* sw, float* sb)
{
    int type = (blockIdx.x >= 450) ? 1 : 0;
    int chunk = blockIdx.x - type * 450;
    const int nslot = type ? 12 : 16;

    for (int i = threadIdx.x; i < TAPS_D * nslot; i += 256) {
        int tap = i / nslot, j = i - tap * nslot;
        int o = type ? 16 + j : j;
        float v = 0.0f;
        if (o < 18) v = getv(off_w, (long)o * TAPS_D + tap);
        else if (o < 27) v = getv(mod_w, (long)(o - 18) * TAPS_D + tap);
        sw[tap * nslot + j] = v;
    }
    if (threadIdx.x < nslot) {
        int o = (type ? 16 : 0) + threadIdx.x;
        sb[threadIdx.x] = (o < 18) ? getv(off_b, o)
                        : (o < 27 ? getv(mod_b, o - 18) : 0.0f);
    }
    __syncthreads();

    int og = threadIdx.x >> 6, lane = threadIdx.x & 63;
    long p0 = ((long)chunk * 64 + lane) * 4;
    int b = (int)(p0 / HWc);
    int p = (int)(p0 - (long)b * HWc);
    int y = p / Wc, x0 = p - (p / Wc) * Wc;

    const int per = type ? 3 : 4;
    int jbase = og * per;

    float acc[4][4];
#pragma unroll
    for (int j = 0; j < 4; j++) {
        float bv = (j < per) ? sb[jbase + j] : 0.0f;
#pragma unroll
        for (int px = 0; px < 4; px++) acc[j][px] = bv;
    }

    const float* xb = xcat + (long)b * CIN_D * HWc;
    if (type == 0) {
#pragma unroll 2
        for (int cin = 0; cin < CIN_D; cin++) {
            const float* xc = xb + (long)cin * HWc;
#pragma unroll
            for (int ky = 0; ky < 3; ky++) {
                int yy = y + ky - 1;
                if (yy < 0 || yy >= Hc) continue;
                const float* row = xc + (long)yy * Wc;
                float xs[6];
                xs[0] = (x0 > 0) ? row[x0 - 1] : 0.0f;
                load4(row, x0, &xs[1]);
                xs[5] = (x0 + 4 < Wc) ? row[x0 + 4] : 0.0f;
#pragma unroll
                for (int kx = 0; kx < 3; kx++) {
                    int tap = (cin * 3 + ky) * 3 + kx;
                    const float4 wq = *(const float4*)&sw[tap * 16 + jbase];
#pragma unroll
                    for (int px = 0; px < 4; px++) {
                        float v = xs[px + kx];
                        acc[0][px] += wq.x * v;
                        acc[1][px] += wq.y * v;
                        acc[2][px] += wq.z * v;
                        acc[3][px] += wq.w * v;
                    }
                }
            }
        }
    } else {
#pragma unroll 2
        for (int cin = 0; cin < CIN_D; cin++) {
            const float* xc = xb + (long)cin * HWc;
#pragma unroll
            for (int ky = 0; ky < 3; ky++) {
                int yy = y + ky - 1;
                if (yy < 0 || yy >= Hc) continue;
                const float* row = xc + (long)yy * Wc;
                float xs[6];
                xs[0] = (x0 > 0) ? row[x0 - 1] : 0.0f;
                load4(row, x0, &xs[1]);
                xs[5] = (x0 + 2 < Wc) ? row[x0 + 4] : 0.0f;
                xs[5] = (x0 + 4 < Wc) ? row[x0 + 4] : 0.0f;
#pragma unroll
                for (int kx = 0; kx < 3; kx++) {
                    int tap = (cin * 3 + ky) * 3 + kx;
                    const float* wp = &sw[tap * 12 + jbase];
                    float w0 = wp[0], w1 = wp[1], w2 = wp[2];
#pragma unroll
                    for (int px = 0; px < 4; px++) {
                        float v = xs[px + kx];
                        acc[0][px] += w0 * v;
                        acc[1][px] += w1 * v;
                        acc[2][px] += w2 * v;
                    }
                }
            }
        }
    }

    long pbase = (long)y * Wc + x0;
#pragma unroll
    for (int j = 0; j < 4; j++) {
        if (j >= per) break;
        int o = (type ? 16 : 0) + jbase + j;
        if (o >= 27) break;
        if (o < 18) {
            *(float4*)(offbuf + ((long)b * 18 + o) * HWc + pbase) =
                make_float4(acc[j][0], acc[j][1], acc[j][2], acc[j][3]);
        } else {
            *(float4*)(maskbuf + ((long)b * 9 + (o - 18)) * HWc + pbase) =
                make_float4(2.0f * sigm(acc[j][0]), 2.0f * sigm(acc[j][1]),
                            2.0f * sigm(acc[j][2]), 2.0f * sigm(acc[j][3]));
        }
    }
}

__global__ void __launch_bounds__(256) k_offmod(
    const float* xcat, const void* off_w, const void* off_b,
    const void* mod_w, const void* mod_b, const int* __restrict__ flag,
    float* offbuf, float* maskbuf)
{
    __shared__ float sw[TAPS_D * 16];  // 36.9 KB (type A); type B uses 27.6 KB
    __shared__ float sb[16];
    if (flag[0])
        offmod6_body<bf16>(xcat, (const bf16*)off_w, (const bf16*)off_b,
                           (const bf16*)mod_w, (const bf16*)mod_b, offbuf, maskbuf, sw, sb);
    else
        offmod6_body<float>(xcat, (const float*)off_w, (const float*)off_b,
                            (const float*)mod_w, (const float*)mod_b, offbuf, maskbuf, sw, sb);
}

// ---------------------------------------------------------------------------
// deform v3 (proven R11 cin-outer structure, unchanged).
// ---------------------------------------------------------------------------
template <typename T>
__device__ __forceinline__ void deform3_body(
    const float* __restrict__ xcat, const float* __restrict__ offbuf,
    const float* __restrict__ maskbuf,
    const T* __restrict__ def_w, const T* __restrict__ def_b,
    float* __restrict__ dcout, float* sw, float* sb)
{
    for (int i = threadIdx.x; i < NKc * TAPS_D; i += 256) {
        int co = i / TAPS_D;
        int tap = i - co * TAPS_D;
        sw[tap * NKc + co] = getv(def_w, i);
    }
    if (threadIdx.x < NKc) sb[threadIdx.x] = getv(def_b, threadIdx.x);
    __syncthreads();

    int idx = blockIdx.x * 256 + threadIdx.x;
    int b = idx / HWc;
    int p = idx - b * HWc;
    int y = p / Wc, x = p - (p / Wc) * Wc;

    float w00[9], w01[9], w10[9], w11[9];
    int i00[9], i01[9], i10[9], i11[9];
#pragma unroll
    for (int k = 0; k < 9; k++) {
        int ky = k / 3, kx = k - (k / 3) * 3;
        float dy = offbuf[((long)b * 18 + 2 * k) * HWc + p];
        float dx = offbuf[((long)b * 18 + 2 * k + 1) * HWc + p];
        float m = maskbuf[((long)b * 9 + k) * HWc + p];
        float py = (float)(y - 1 + ky) + dy;
        float px = (float)(x - 1 + kx) + dx;
        float y0f = floorf(py), x0f = floorf(px);
        int y0 = (int)y0f, x0 = (int)x0f;
        float wy1 = py - y0f, wx1 = px - x0f;
        float a00 = (1.0f - wy1) * (1.0f - wx1) * m;
        float a01 = (1.0f - wy1) * wx1 * m;
        float a10 = wy1 * (1.0f - wx1) * m;
        float a11 = wy1 * wx1 * m;
        bool vy0 = (y0 >= 0) && (y0 < Hc);
        bool vy1 = (y0 + 1 >= 0) && (y0 + 1 < Hc);
        bool vx0 = (x0 >= 0) && (x0 < Wc);
        bool vx1 = (x0 + 1 >= 0) && (x0 + 1 < Wc);
        w00[k] = (vy0 && vx0) ? a00 : 0.0f;
        w01[k] = (vy0 && vx1) ? a01 : 0.0f;
        w10[k] = (vy1 && vx0) ? a10 : 0.0f;
        w11[k] = (vy1 && vx1) ? a11 : 0.0f;
        int yc0 = min(max(y0, 0), Hc - 1);
        int yc1 = min(max(y0 + 1, 0), Hc - 1);
        int xc0 = min(max(x0, 0), Wc - 1);
        int xc1 = min(max(x0 + 1, 0), Wc - 1);
        i00[k] = yc0 * Wc + xc0; i01[k] = yc0 * Wc + xc1;
        i10[k] = yc1 * Wc + xc0; i11[k] = yc1 * Wc + xc1;
    }

    float acc[NKc];
#pragma unroll
    for (int i = 0; i < NKc; i++) acc[i] = sb[i];

    const float* xb = xcat + (long)b * CIN_D * HWc;
#pragma unroll 1
    for (int cin = 0; cin < CIN_D; cin++) {
        const float* xc = xb + (long)cin * HWc;
        float s[9];
#pragma unroll
        for (int k = 0; k < 9; k++)
            s[k] = w00[k] * xc[i00[k]] + w01[k] * xc[i01[k]] +
                   w10[k] * xc[i10[k]] + w11[k] * xc[i11[k]];
#pragma unroll
        for (int k = 0; k < 9; k++) {
            const float* wrow = &sw[(cin * 9 + k) * NKc];
#pragma unroll
            for (int co = 0; co < NKc; co++) acc[co] += wrow[co] * s[k];
        }
    }

#pragma unroll
    for (int co = 0; co < NKc; co++)
        dcout[((long)b * NKc + co) * HWc + p] = acc[co];
}

__global__ void __launch_bounds__(256) k_deform(
    const float* xcat, const float* offbuf, const float* maskbuf,
    const void* def_w, const void* def_b, const int* __restrict__ flag,
    float* dcout)
{
    __shared__ float sw[TAPS_D * NKc];  // 36.9 KB
    __shared__ float sb[NKc];
    if (flag[0])
        deform3_body<bf16>(xcat, offbuf, maskbuf, (const bf16*)def_w, (const bf16*)def_b,
                           dcout, sw, sb);
    else
        deform3_body<float>(xcat, offbuf, maskbuf, (const float*)def_w, (const float*)def_b,
                            dcout, sw, sb);
}

// ---------------------------------------------------------------------------
// outconv v5 (ROUND-12): output-split across TWO block types (24 outputs each)
// to fix wave starvation (was 450 blocks = 1.76/CU). Grid 900. Block 256 =
// 4 og x 64 lanes x 4 px; per og 6 outputs in 8-slot padded LDS rows ->
// aligned b128 + b64 per tap feeding 24 FMAs. LDS 18.4 KB.
// ---------------------------------------------------------------------------
template <typename T>
__device__ __forceinline__ void outconv6_body(
    const float* __restrict__ dcout, const T* __restrict__ out_w,
    const T* __restrict__ out_b, T* __restrict__ out, float* sw, float* sb)
{
    int type = (blockIdx.x >= 450) ? 1 : 0;
    int chunk = blockIdx.x - type * 450;

    for (int i = threadIdx.x; i < 24 * TAPS_O; i += 256) {
        int o = i / TAPS_O, tap = i - o * TAPS_O;
        int slot = (o / 6) * 8 + (o % 6);
        sw[tap * 32 + slot] = getv(out_w, (long)(type * 24 + o) * TAPS_O + tap);
    }
    if (threadIdx.x < 24) sb[threadIdx.x] = getv(out_b, type * 24 + threadIdx.x);
    __syncthreads();

    int og = threadIdx.x >> 6, lane = threadIdx.x & 63;
    long p0 = ((long)chunk * 64 + lane) * 4;
    int b = (int)(p0 / HWc);
    int p = (int)(p0 - (long)b * HWc);
    int y = p / Wc, x0 = p - (p / Wc) * Wc;

    float acc[6][4];
#pragma unroll
    for (int j = 0; j < 6; j++) {
        float bv = sb[og * 6 + j];
#pragma unroll
        for (int px = 0; px < 4; px++) acc[j][px] = bv;
    }

    const float* xb = dcout + (long)b * NKc * HWc;
#pragma unroll 2
    for (int cin = 0; cin < NKc; cin++) {
        const float* xc = xb + (long)cin * HWc;
#pragma unroll
        for (int ky = 0; ky < 3; ky++) {
            int yy = y + ky - 1;
            if (yy < 0 || yy >= Hc) continue;
            const float* row = xc + (long)yy * Wc;
            float xs[6];
            xs[0] = (x0 > 0) ? row[x0 - 1] : 0.0f;
            load4(row, x0, &xs[1]);
            xs[5] = (x0 + 4 < Wc) ? row[x0 + 4] : 0.0f;
#pragma unroll
            for (int kx = 0; kx < 3; kx++) {
                int tap = (cin * 3 + ky) * 3 + kx;
                const float* wp = &sw[tap * 32 + og * 8];
                const float4 w0 = *(const float4*)wp;
                const float2 w1 = *(const float2*)(wp + 4);
#pragma unroll
                for (int px = 0; px < 4; px++) {
                    float v = xs[px + kx];
                    acc[0][px] += w0.x * v;  acc[1][px] += w0.y * v;
                    acc[2][px] += w0.z * v;  acc[3][px] += w0.w * v;
                    acc[4][px] += w1.x * v;  acc[5][px] += w1.y * v;
                }
            }
        }
    }

    // pixel shuffle: co = cc*16 + ii*4 + jj -> out[b, cc, y*4+ii, x*4+jj]
#pragma unroll
    for (int j = 0; j < 6; j++) {
        int co = type * 24 + og * 6 + j;
        int cc = co >> 4;
        int r = co & 15;
        int ii = r >> 2, jj = r & 3;
        long ob = (((long)b * 3 + cc) * (Hc * 4) + (y * 4 + ii)) * (long)(Wc * 4);
#pragma unroll
        for (int px = 0; px < 4; px++) {
            float v = fminf(fmaxf(acc[j][px], 0.0f), 255.0f);
            putv(out, ob + (x0 + px) * 4 + jj, v);
        }
    }
}

__global__ void __launch_bounds__(256) k_outconv(
    const float* dcout, const void* out_w, const void* out_b,
    const int* __restrict__ flag, void* out)
{
    __shared__ float sw[TAPS_O * 32];  // 18.4 KB
    __shared__ float sb[24];
    if (flag[0])
        outconv6_body<bf16>(dcout, (const bf16*)out_w, (const bf16*)out_b, (bf16*)out, sw, sb);
    else
        outconv6_body<float>(dcout, (const float*)out_w, (const float*)out_b, (float*)out, sw, sb);
}

extern "C" void kernel_launch(void* const* d_in, const int* in_sizes, int n_in,
                              void* d_out, int out_size, void* d_ws, size_t ws_size,
                              hipStream_t stream) {
    const void* X      = d_in[0];
    const void* lstm_w = d_in[1];
    const void* lstm_b = d_in[2];
    const void* Wci    = d_in[3];
    const void* Wcf    = d_in[4];
    const void* Wco    = d_in[5];
    const void* off_w  = d_in[6];
    const void* off_b  = d_in[7];
    const void* mod_w  = d_in[8];
    const void* mod_b  = d_in[9];
    const void* def_w  = d_in[10];
    const void* def_b  = d_in[11];
    const void* out_w  = d_in[12];
    const void* out_b  = d_in[13];

    int* flag = (int*)d_ws;
    float* W = (float*)d_ws + 64;
    size_t o = 0;
    float* c_buf   = W + o; o += (size_t)Bn * NKc * HWc;
    float* xcat    = W + o; o += (size_t)Bn * CIN_D * HWc;
    float* offbuf  = W + o; o += (size_t)Bn * 18 * HWc;
    float* maskbuf = W + o; o += (size_t)Bn * 9 * HWc;
    float* dcout   = W + o; o += (size_t)Bn * NKc * HWc;

    dim3 blk(256);
    dim3 gridP(NPIX / 256);           // 450
    dim3 gridL(Bn * Hc * 5);          // 1800
    dim3 gridC2(2 * (NPIX / 4 / 64)); // 900

    k_detect<<<1, blk, 0, stream>>>(lstm_w, flag);
    for (int t = 0; t < Tn; t++) {
        k_lstm2<<<gridL, blk, 0, stream>>>(X, lstm_w, lstm_b, Wci, Wcf, Wco,
                                           flag, c_buf, xcat, t);
    }
    k_offmod<<<gridC2, blk, 0, stream>>>(xcat, off_w, off_b, mod_w, mod_b, flag,
                                         offbuf, maskbuf);
    k_deform<<<gridP, blk, 0, stream>>>(xcat, offbuf, maskbuf, def_w, def_b, flag, dcout);
    k_outconv<<<gridC2, blk, 0, stream>>>(dcout, out_w, out_b, flag, d_out);
}

// Round 13
// 758.078 us; speedup vs baseline: 1.0329x; 1.0329x over previous
//
#include <hip/hip_runtime.h>
#include <hip/hip_bf16.h>

// Problem dims
#define Bn 2
#define Tn 4
#define NCc 3
#define NKc 16
#define Hc 180
#define Wc 320
#define HWc (Hc * Wc)          // 57600
#define NPIX (Bn * HWc)        // 115200
#define CIN_LSTM 19            // NC + NK
#define GATES 64               // 4*NK
#define CIN_D 64               // T*NK
#define TAPS_L (CIN_LSTM * 9)  // 171
#define TAPS_D (CIN_D * 9)     // 576
#define TAPS_O (NKc * 9)       // 144

typedef __hip_bfloat16 bf16;

__device__ __forceinline__ float getv(const float* p, long i) { return p[i]; }
__device__ __forceinline__ float getv(const bf16* p, long i) {
    unsigned int u = ((unsigned int)((const unsigned short*)p)[i]) << 16;
    return __uint_as_float(u);
}
__device__ __forceinline__ void putv(float* p, long i, float v) { p[i] = v; }
__device__ __forceinline__ void putv(bf16* p, long i, float v) { p[i] = __float2bfloat16(v); }
__device__ __forceinline__ float sigm(float x) { return 1.0f / (1.0f + __expf(-x)); }
__device__ __forceinline__ float tanh_(float x) { return 1.0f - 2.0f / (__expf(2.0f * x) + 1.0f); }

__device__ __forceinline__ void load4(const float* row, int x0, float* d) {
    const float4 v = *(const float4*)(row + x0);
    d[0] = v.x; d[1] = v.y; d[2] = v.z; d[3] = v.w;
}
__device__ __forceinline__ void load4(const bf16* row, int x0, float* d) {
    ushort4 u = *(const ushort4*)((const unsigned short*)row + x0);
    d[0] = __uint_as_float(((unsigned int)u.x) << 16);
    d[1] = __uint_as_float(((unsigned int)u.y) << 16);
    d[2] = __uint_as_float(((unsigned int)u.z) << 16);
    d[3] = __uint_as_float(((unsigned int)u.w) << 16);
}

// ---------------------------------------------------------------------------
// Dtype probe (bf16 vs float32 inputs) -> flag in d_ws.
// ---------------------------------------------------------------------------
__global__ void __launch_bounds__(256) k_detect(const void* lstm_w_raw, int* flag)
{
    __shared__ int bad;
    if (threadIdx.x == 0) bad = 0;
    __syncthreads();
    const unsigned short* u = (const unsigned short*)lstm_w_raw;
    int local = 0;
    for (int i = threadIdx.x; i < GATES * TAPS_L; i += 256) {
        unsigned int f32 = ((unsigned int)u[i]) << 16;
        float v = __uint_as_float(f32);
        if (!(fabsf(v) <= 64.0f)) local = 1;
    }
    if (local) atomicOr(&bad, 1);
    __syncthreads();
    if (threadIdx.x == 0) flag[0] = bad ? 0 : 1;
}

// ---------------------------------------------------------------------------
// ConvLSTM step (ROUND-13): TWO OUTPUT ROWS PER BLOCK.
// Block 256 = 16 kc x 16 lanes(4px); block covers rows {y0, y0+1} of one
// 64-px segment -> grid 900. Per cin: load 4 rows once (12 loads vs 18),
// each b128 weight read feeds 32 FMAs (2 rows), staging runs 900x not 1800x.
// Per-pixel math identical to the proven R8 body.
// ---------------------------------------------------------------------------
template <typename S>
__device__ __forceinline__ void conv_plane2r(
    const S* __restrict__ src, int cin, int y0, int x0, int kc,
    const float* __restrict__ sw, float (&acc)[2][4][4])
{
    float xs[4][6];  // rows y0-1 .. y0+2
#pragma unroll
    for (int r = 0; r < 4; r++) {
        int yy = y0 - 1 + r;
        if (yy >= 0 && yy < Hc) {
            const S* row = src + (long)yy * Wc;
            xs[r][0] = (x0 > 0) ? getv(row, x0 - 1) : 0.0f;
            load4(row, x0, &xs[r][1]);
            xs[r][5] = (x0 + 4 < Wc) ? getv(row, x0 + 4) : 0.0f;
        } else {
#pragma unroll
            for (int j = 0; j < 6; j++) xs[r][j] = 0.0f;
        }
    }
#pragma unroll
    for (int ky = 0; ky < 3; ky++) {
#pragma unroll
        for (int kx = 0; kx < 3; kx++) {
            int tap = (cin * 3 + ky) * 3 + kx;
            const float4 wq = *(const float4*)&sw[(tap * 16 + kc) * 4];
#pragma unroll
            for (int px = 0; px < 4; px++) {
                float v0 = xs[ky][px + kx];      // output row y0
                float v1 = xs[ky + 1][px + kx];  // output row y0+1
                acc[0][0][px] += wq.x * v0;  acc[1][0][px] += wq.x * v1;
                acc[0][1][px] += wq.y * v0;  acc[1][1][px] += wq.y * v1;
                acc[0][2][px] += wq.z * v0;  acc[1][2][px] += wq.z * v1;
                acc[0][3][px] += wq.w * v0;  acc[1][3][px] += wq.w * v1;
            }
        }
    }
}

template <typename T>
__device__ __forceinline__ void lstm2r_body(
    const T* __restrict__ X, const T* __restrict__ lstm_w, const T* __restrict__ lstm_b,
    const T* __restrict__ Wci, const T* __restrict__ Wcf, const T* __restrict__ Wco,
    float* __restrict__ c_buf, float* __restrict__ xcat, int t,
    float* sw, float* sb)
{
    for (int i = threadIdx.x; i < GATES * TAPS_L; i += 256) {
        int co = i / TAPS_L, tap = i - co * TAPS_L;
        int kc = co & 15, g = co >> 4;
        sw[(tap * 16 + kc) * 4 + g] = getv(lstm_w, i);
    }
    if (threadIdx.x < GATES) sb[threadIdx.x] = getv(lstm_b, threadIdx.x);
    __syncthreads();

    int blk = blockIdx.x;                 // 900 = Bn * 90 * 5
    int seg = blk % 5; int rem = blk / 5;
    int yp = rem % 90; int b = rem / 90;
    int y0 = yp * 2;
    int kc = threadIdx.x >> 4, pl = threadIdx.x & 15;
    int x0 = seg * 64 + pl * 4;

    float acc[2][4][4];  // [row][gate][px]
#pragma unroll
    for (int px = 0; px < 4; px++) {
#pragma unroll
        for (int r = 0; r < 2; r++) {
            acc[r][0][px] = sb[kc];
            acc[r][1][px] = sb[16 + kc];
            acc[r][2][px] = sb[32 + kc];
            acc[r][3][px] = sb[48 + kc];
        }
    }

    const T* xt = X + (long)(b * Tn + t) * NCc * HWc;
#pragma unroll
    for (int cin = 0; cin < NCc; cin++)
        conv_plane2r(xt + (long)cin * HWc, cin, y0, x0, kc, sw, acc);
    if (t > 0) {
        const float* hp = xcat + ((long)b * CIN_D + (t - 1) * NKc) * HWc;
#pragma unroll 1
        for (int cin = 0; cin < NKc; cin++)
            conv_plane2r(hp + (long)cin * HWc, cin + NCc, y0, x0, kc, sw, acc);
    }

#pragma unroll
    for (int r = 0; r < 2; r++) {
        int y = y0 + r;
        long pbase = (long)y * Wc + x0;
        float* cb = c_buf + (long)(b * NKc + kc) * HWc + pbase;
        float cprev[4];
        if (t > 0) {
            const float4 cv = *(const float4*)cb;
            cprev[0] = cv.x; cprev[1] = cv.y; cprev[2] = cv.z; cprev[3] = cv.w;
        } else {
            cprev[0] = cprev[1] = cprev[2] = cprev[3] = 0.0f;
        }
        float wci[4], wcf[4], wco[4];
        load4(Wci + (long)kc * HWc + pbase, 0, wci);
        load4(Wcf + (long)kc * HWc + pbase, 0, wcf);
        load4(Wco + (long)kc * HWc + pbase, 0, wco);

        float cn4[4], h4[4];
#pragma unroll
        for (int px = 0; px < 4; px++) {
            float ii = sigm(acc[r][0][px] + wci[px] * cprev[px]);
            float ff = sigm(acc[r][1][px] + wcf[px] * cprev[px]);
            float cn = ff * cprev[px] + ii * tanh_(acc[r][2][px]);
            float oo = sigm(acc[r][3][px] + wco[px] * cn);
            cn4[px] = cn; h4[px] = oo * tanh_(cn);
        }
        *(float4*)cb = make_float4(cn4[0], cn4[1], cn4[2], cn4[3]);
        *(float4*)(xcat + ((long)b * CIN_D + t * NKc + kc) * HWc + pbase) =
            make_float4(h4[0], h4[1], h4[2], h4[3]);
    }
}

__global__ void __launch_bounds__(256) k_lstm2(
    const void* X, const void* lstm_w, const void* lstm_b,
    const void* Wci, const void* Wcf, const void* Wco,
    const int* __restrict__ flag,
    float* c_buf, float* xcat, int t)
{
    __shared__ float sw[TAPS_L * GATES];  // 43.8 KB
    __shared__ float sb[GATES];
    if (flag[0])
        lstm2r_body<bf16>((const bf16*)X, (const bf16*)lstm_w, (const bf16*)lstm_b,
                          (const bf16*)Wci, (const bf16*)Wcf, (const bf16*)Wco,
                          c_buf, xcat, t, sw, sb);
    else
        lstm2r_body<float>((const float*)X, (const float*)lstm_w, (const float*)lstm_b,
                           (const float*)Wci, (const float*)Wcf, (const float*)Wco,
                           c_buf, xcat, t, sw, sb);
}

// ---------------------------------------------------------------------------
// offmod v6 (proven R10/R12 output-split structure, unchanged).
// ---------------------------------------------------------------------------
template <typename T>
__device__ __forceinline__ void offmod6_body(
    const float* __restrict__ xcat,
    const T* __restrict__ off_w, const T* __restrict__ off_b,
    const T* __restrict__ mod_w, const T* __restrict__ mod_b,
    float* __restrict__ offbuf, float* __restrict__ maskbuf,
    float* sw, float* sb)
{
    int type = (blockIdx.x >= 450) ? 1 : 0;
    int chunk = blockIdx.x - type * 450;
    const int nslot = type ? 12 : 16;

    for (int i = threadIdx.x; i < TAPS_D * nslot; i += 256) {
        int tap = i / nslot, j = i - tap * nslot;
        int o = type ? 16 + j : j;
        float v = 0.0f;
        if (o < 18) v = getv(off_w, (long)o * TAPS_D + tap);
        else if (o < 27) v = getv(mod_w, (long)(o - 18) * TAPS_D + tap);
        sw[tap * nslot + j] = v;
    }
    if (threadIdx.x < nslot) {
        int o = (type ? 16 : 0) + threadIdx.x;
        sb[threadIdx.x] = (o < 18) ? getv(off_b, o)
                        : (o < 27 ? getv(mod_b, o - 18) : 0.0f);
    }
    __syncthreads();

    int og = threadIdx.x >> 6, lane = threadIdx.x & 63;
    long p0 = ((long)chunk * 64 + lane) * 4;
    int b = (int)(p0 / HWc);
    int p = (int)(p0 - (long)b * HWc);
    int y = p / Wc, x0 = p - (p / Wc) * Wc;

    const int per = type ? 3 : 4;
    int jbase = og * per;

    float acc[4][4];
#pragma unroll
    for (int j = 0; j < 4; j++) {
        float bv = (j < per) ? sb[jbase + j] : 0.0f;
#pragma unroll
        for (int px = 0; px < 4; px++) acc[j][px] = bv;
    }

    const float* xb = xcat + (long)b * CIN_D * HWc;
    if (type == 0) {
#pragma unroll 2
        for (int cin = 0; cin < CIN_D; cin++) {
            const float* xc = xb + (long)cin * HWc;
#pragma unroll
            for (int ky = 0; ky < 3; ky++) {
                int yy = y + ky - 1;
                if (yy < 0 || yy >= Hc) continue;
                const float* row = xc + (long)yy * Wc;
                float xs[6];
                xs[0] = (x0 > 0) ? row[x0 - 1] : 0.0f;
                load4(row, x0, &xs[1]);
                xs[5] = (x0 + 4 < Wc) ? row[x0 + 4] : 0.0f;
#pragma unroll
                for (int kx = 0; kx < 3; kx++) {
                    int tap = (cin * 3 + ky) * 3 + kx;
                    const float4 wq = *(const float4*)&sw[tap * 16 + jbase];
#pragma unroll
                    for (int px = 0; px < 4; px++) {
                        float v = xs[px + kx];
                        acc[0][px] += wq.x * v;
                        acc[1][px] += wq.y * v;
                        acc[2][px] += wq.z * v;
                        acc[3][px] += wq.w * v;
                    }
                }
            }
        }
    } else {
#pragma unroll 2
        for (int cin = 0; cin < CIN_D; cin++) {
            const float* xc = xb + (long)cin * HWc;
#pragma unroll
            for (int ky = 0; ky < 3; ky++) {
                int yy = y + ky - 1;
                if (yy < 0 || yy >= Hc) continue;
                const float* row = xc + (long)yy * Wc;
                float xs[6];
                xs[0] = (x0 > 0) ? row[x0 - 1] : 0.0f;
                load4(row, x0, &xs[1]);
                xs[5] = (x0 + 4 < Wc) ? row[x0 + 4] : 0.0f;
#pragma unroll
                for (int kx = 0; kx < 3; kx++) {
                    int tap = (cin * 3 + ky) * 3 + kx;
                    const float* wp = &sw[tap * 12 + jbase];
                    float w0 = wp[0], w1 = wp[1], w2 = wp[2];
#pragma unroll
                    for (int px = 0; px < 4; px++) {
                        float v = xs[px + kx];
                        acc[0][px] += w0 * v;
                        acc[1][px] += w1 * v;
                        acc[2][px] += w2 * v;
                    }
                }
            }
        }
    }

    long pbase = (long)y * Wc + x0;
#pragma unroll
    for (int j = 0; j < 4; j++) {
        if (j >= per) break;
        int o = (type ? 16 : 0) + jbase + j;
        if (o >= 27) break;
        if (o < 18) {
            *(float4*)(offbuf + ((long)b * 18 + o) * HWc + pbase) =
                make_float4(acc[j][0], acc[j][1], acc[j][2], acc[j][3]);
        } else {
            *(float4*)(maskbuf + ((long)b * 9 + (o - 18)) * HWc + pbase) =
                make_float4(2.0f * sigm(acc[j][0]), 2.0f * sigm(acc[j][1]),
                            2.0f * sigm(acc[j][2]), 2.0f * sigm(acc[j][3]));
        }
    }
}

__global__ void __launch_bounds__(256) k_offmod(
    const float* xcat, const void* off_w, const void* off_b,
    const void* mod_w, const void* mod_b, const int* __restrict__ flag,
    float* offbuf, float* maskbuf)
{
    __shared__ float sw[TAPS_D * 16];  // 36.9 KB (type A); type B uses 27.6 KB
    __shared__ float sb[16];
    if (flag[0])
        offmod6_body<bf16>(xcat, (const bf16*)off_w, (const bf16*)off_b,
                           (const bf16*)mod_w, (const bf16*)mod_b, offbuf, maskbuf, sw, sb);
    else
        offmod6_body<float>(xcat, (const float*)off_w, (const float*)off_b,
                            (const float*)mod_w, (const float*)mod_b, offbuf, maskbuf, sw, sb);
}

// ---------------------------------------------------------------------------
// deform v3 (proven R11 cin-outer structure, unchanged).
// ---------------------------------------------------------------------------
template <typename T>
__device__ __forceinline__ void deform3_body(
    const float* __restrict__ xcat, const float* __restrict__ offbuf,
    const float* __restrict__ maskbuf,
    const T* __restrict__ def_w, const T* __restrict__ def_b,
    float* __restrict__ dcout, float* sw, float* sb)
{
    for (int i = threadIdx.x; i < NKc * TAPS_D; i += 256) {
        int co = i / TAPS_D;
        int tap = i - co * TAPS_D;
        sw[tap * NKc + co] = getv(def_w, i);
    }
    if (threadIdx.x < NKc) sb[threadIdx.x] = getv(def_b, threadIdx.x);
    __syncthreads();

    int idx = blockIdx.x * 256 + threadIdx.x;
    int b = idx / HWc;
    int p = idx - b * HWc;
    int y = p / Wc, x = p - (p / Wc) * Wc;

    float w00[9], w01[9], w10[9], w11[9];
    int i00[9], i01[9], i10[9], i11[9];
#pragma unroll
    for (int k = 0; k < 9; k++) {
        int ky = k / 3, kx = k - (k / 3) * 3;
        float dy = offbuf[((long)b * 18 + 2 * k) * HWc + p];
        float dx = offbuf[((long)b * 18 + 2 * k + 1) * HWc + p];
        float m = maskbuf[((long)b * 9 + k) * HWc + p];
        float py = (float)(y - 1 + ky) + dy;
        float px = (float)(x - 1 + kx) + dx;
        float y0f = floorf(py), x0f = floorf(px);
        int y0 = (int)y0f, x0 = (int)x0f;
        float wy1 = py - y0f, wx1 = px - x0f;
        float a00 = (1.0f - wy1) * (1.0f - wx1) * m;
        float a01 = (1.0f - wy1) * wx1 * m;
        float a10 = wy1 * (1.0f - wx1) * m;
        float a11 = wy1 * wx1 * m;
        bool vy0 = (y0 >= 0) && (y0 < Hc);
        bool vy1 = (y0 + 1 >= 0) && (y0 + 1 < Hc);
        bool vx0 = (x0 >= 0) && (x0 < Wc);
        bool vx1 = (x0 + 1 >= 0) && (x0 + 1 < Wc);
        w00[k] = (vy0 && vx0) ? a00 : 0.0f;
        w01[k] = (vy0 && vx1) ? a01 : 0.0f;
        w10[k] = (vy1 && vx0) ? a10 : 0.0f;
        w11[k] = (vy1 && vx1) ? a11 : 0.0f;
        int yc0 = min(max(y0, 0), Hc - 1);
        int yc1 = min(max(y0 + 1, 0), Hc - 1);
        int xc0 = min(max(x0, 0), Wc - 1);
        int xc1 = min(max(x0 + 1, 0), Wc - 1);
        i00[k] = yc0 * Wc + xc0; i01[k] = yc0 * Wc + xc1;
        i10[k] = yc1 * Wc + xc0; i11[k] = yc1 * Wc + xc1;
    }

    float acc[NKc];
#pragma unroll
    for (int i = 0; i < NKc; i++) acc[i] = sb[i];

    const float* xb = xcat + (long)b * CIN_D * HWc;
#pragma unroll 1
    for (int cin = 0; cin < CIN_D; cin++) {
        const float* xc = xb + (long)cin * HWc;
        float s[9];
#pragma unroll
        for (int k = 0; k < 9; k++)
            s[k] = w00[k] * xc[i00[k]] + w01[k] * xc[i01[k]] +
                   w10[k] * xc[i10[k]] + w11[k] * xc[i11[k]];
#pragma unroll
        for (int k = 0; k < 9; k++) {
            const float* wrow = &sw[(cin * 9 + k) * NKc];
#pragma unroll
            for (int co = 0; co < NKc; co++) acc[co] += wrow[co] * s[k];
        }
    }

#pragma unroll
    for (int co = 0; co < NKc; co++)
        dcout[((long)b * NKc + co) * HWc + p] = acc[co];
}

__global__ void __launch_bounds__(256) k_deform(
    const float* xcat, const float* offbuf, const float* maskbuf,
    const void* def_w, const void* def_b, const int* __restrict__ flag,
    float* dcout)
{
    __shared__ float sw[TAPS_D * NKc];  // 36.9 KB
    __shared__ float sb[NKc];
    if (flag[0])
        deform3_body<bf16>(xcat, offbuf, maskbuf, (const bf16*)def_w, (const bf16*)def_b,
                           dcout, sw, sb);
    else
        deform3_body<float>(xcat, offbuf, maskbuf, (const float*)def_w, (const float*)def_b,
                            dcout, sw, sb);
}

// ---------------------------------------------------------------------------
// outconv v5 (proven R12 type-split structure, unchanged).
// ---------------------------------------------------------------------------
template <typename T>
__device__ __forceinline__ void outconv6_body(
    const float* __restrict__ dcout, const T* __restrict__ out_w,
    const T* __restrict__ out_b, T* __restrict__ out, float* sw, float* sb)
{
    int type = (blockIdx.x >= 450) ? 1 : 0;
    int chunk = blockIdx.x - type * 450;

    for (int i = threadIdx.x; i < 24 * TAPS_O; i += 256) {
        int o = i / TAPS_O, tap = i - o * TAPS_O;
        int slot = (o / 6) * 8 + (o % 6);
        sw[tap * 32 + slot] = getv(out_w, (long)(type * 24 + o) * TAPS_O + tap);
    }
    if (threadIdx.x < 24) sb[threadIdx.x] = getv(out_b, type * 24 + threadIdx.x);
    __syncthreads();

    int og = threadIdx.x >> 6, lane = threadIdx.x & 63;
    long p0 = ((long)chunk * 64 + lane) * 4;
    int b = (int)(p0 / HWc);
    int p = (int)(p0 - (long)b * HWc);
    int y = p / Wc, x0 = p - (p / Wc) * Wc;

    float acc[6][4];
#pragma unroll
    for (int j = 0; j < 6; j++) {
        float bv = sb[og * 6 + j];
#pragma unroll
        for (int px = 0; px < 4; px++) acc[j][px] = bv;
    }

    const float* xb = dcout + (long)b * NKc * HWc;
#pragma unroll 2
    for (int cin = 0; cin < NKc; cin++) {
        const float* xc = xb + (long)cin * HWc;
#pragma unroll
        for (int ky = 0; ky < 3; ky++) {
            int yy = y + ky - 1;
            if (yy < 0 || yy >= Hc) continue;
            const float* row = xc + (long)yy * Wc;
            float xs[6];
            xs[0] = (x0 > 0) ? row[x0 - 1] : 0.0f;
            load4(row, x0, &xs[1]);
            xs[5] = (x0 + 4 < Wc) ? row[x0 + 4] : 0.0f;
#pragma unroll
            for (int kx = 0; kx < 3; kx++) {
                int tap = (cin * 3 + ky) * 3 + kx;
                const float* wp = &sw[tap * 32 + og * 8];
                const float4 w0 = *(const float4*)wp;
                const float2 w1 = *(const float2*)(wp + 4);
#pragma unroll
                for (int px = 0; px < 4; px++) {
                    float v = xs[px + kx];
                    acc[0][px] += w0.x * v;  acc[1][px] += w0.y * v;
                    acc[2][px] += w0.z * v;  acc[3][px] += w0.w * v;
                    acc[4][px] += w1.x * v;  acc[5][px] += w1.y * v;
                }
            }
        }
    }

#pragma unroll
    for (int j = 0; j < 6; j++) {
        int co = type * 24 + og * 6 + j;
        int cc = co >> 4;
        int r = co & 15;
        int ii = r >> 2, jj = r & 3;
        long ob = (((long)b * 3 + cc) * (Hc * 4) + (y * 4 + ii)) * (long)(Wc * 4);
#pragma unroll
        for (int px = 0; px < 4; px++) {
            float v = fminf(fmaxf(acc[j][px], 0.0f), 255.0f);
            putv(out, ob + (x0 + px) * 4 + jj, v);
        }
    }
}

__global__ void __launch_bounds__(256) k_outconv(
    const float* dcout, const void* out_w, const void* out_b,
    const int* __restrict__ flag, void* out)
{
    __shared__ float sw[TAPS_O * 32];  // 18.4 KB
    __shared__ float sb[24];
    if (flag[0])
        outconv6_body<bf16>(dcout, (const bf16*)out_w, (const bf16*)out_b, (bf16*)out, sw, sb);
    else
        outconv6_body<float>(dcout, (const float*)out_w, (const float*)out_b, (float*)out, sw, sb);
}

extern "C" void kernel_launch(void* const* d_in, const int* in_sizes, int n_in,
                              void* d_out, int out_size, void* d_ws, size_t ws_size,
                              hipStream_t stream) {
    const void* X      = d_in[0];
    const void* lstm_w = d_in[1];
    const void* lstm_b = d_in[2];
    const void* Wci    = d_in[3];
    const void* Wcf    = d_in[4];
    const void* Wco    = d_in[5];
    const void* off_w  = d_in[6];
    const void* off_b  = d_in[7];
    const void* mod_w  = d_in[8];
    const void* mod_b  = d_in[9];
    const void* def_w  = d_in[10];
    const void* def_b  = d_in[11];
    const void* out_w  = d_in[12];
    const void* out_b  = d_in[13];

    int* flag = (int*)d_ws;
    float* W = (float*)d_ws + 64;
    size_t o = 0;
    float* c_buf   = W + o; o += (size_t)Bn * NKc * HWc;
    float* xcat    = W + o; o += (size_t)Bn * CIN_D * HWc;
    float* offbuf  = W + o; o += (size_t)Bn * 18 * HWc;
    float* maskbuf = W + o; o += (size_t)Bn * 9 * HWc;
    float* dcout   = W + o; o += (size_t)Bn * NKc * HWc;

    dim3 blk(256);
    dim3 gridP(NPIX / 256);           // 450
    dim3 gridL2(Bn * (Hc / 2) * 5);   // 900: 2-row lstm blocks
    dim3 gridC2(2 * (NPIX / 4 / 64)); // 900

    k_detect<<<1, blk, 0, stream>>>(lstm_w, flag);
    for (int t = 0; t < Tn; t++) {
        k_lstm2<<<gridL2, blk, 0, stream>>>(X, lstm_w, lstm_b, Wci, Wcf, Wco,
                                            flag, c_buf, xcat, t);
    }
    k_offmod<<<gridC2, blk, 0, stream>>>(xcat, off_w, off_b, mod_w, mod_b, flag,
                                         offbuf, maskbuf);
    k_deform<<<gridP, blk, 0, stream>>>(xcat, offbuf, maskbuf, def_w, def_b, flag, dcout);
    k_outconv<<<gridC2, blk, 0, stream>>>(dcout, out_w, out_b, flag, d_out);
}